// Round 5
// baseline (1119.257 us; speedup 1.0000x reference)
//
#include <hip/hip_runtime.h>
#include <math.h>

#define BN_EPS 1e-5f
constexpr int COUT = 256;      // output channels of both linears

// ---- KNN config ----
constexpr int QPT   = 4;                 // queries per thread
constexpr int NPART = 8;                 // candidate partitions
constexpr int QPB   = 256 * QPT;         // 1024 queries per block

// ---- GEMM config ----
constexpr int GROWS = 32;    // rows per block tile
constexpr int RPT   = 4;     // rows per thread   (rowg = tid>>5, 8 groups)
constexpr int CPT   = 8;     // cols per thread   (colg = tid&31, 32 groups)
constexpr int KCH   = 128;   // K-chunk staged in LDS

// ---------------------------------------------------------------------------
// GEMM  out[M][256] = relu( (X[M][K] @ W[256][K]^T + b)*scale + shift )
// optionally += 3-NN gather from f2 via (wts, idx).
// 256 threads: thread covers RPT=4 rows x CPT=8 cols; one LDS A-read (b128,
// only 2 distinct addrs/wave -> free 2-way) feeds 32 fmas.
// ---------------------------------------------------------------------------
__global__ __launch_bounds__(256) void gemm_bn_relu_k(
    const float* __restrict__ X, const float* __restrict__ W,
    const float* __restrict__ b, const float* __restrict__ g,
    const float* __restrict__ beta, const float* __restrict__ m,
    const float* __restrict__ v,
    float* __restrict__ out, int M, int K,
    const float* __restrict__ f2,      // nullable: interp source (N2 x 256)
    const float4* __restrict__ wts,    // per-query 3 weights
    const int4* __restrict__ idx)      // per-query 3 global rows into f2
{
    const int tid  = threadIdx.x;
    const int colg = tid & 31;          // 32 col groups
    const int rowg = tid >> 5;          // 8 row groups
    const int c0   = colg * CPT;        // 8 cols
    const int r0   = rowg * RPT;        // 4 rows (tile-local)
    const int row0 = blockIdx.x * GROWS;

    __shared__ float At[GROWS][KCH];    // 16 KB

    float acc[RPT][CPT];
#pragma unroll
    for (int r = 0; r < RPT; ++r)
#pragma unroll
        for (int ci = 0; ci < CPT; ++ci) acc[r][ci] = 0.f;

    for (int k0 = 0; k0 < K; k0 += KCH) {
        // stage A tile (GROWS x KCH): 1024 float4 by 256 threads
        for (int i = tid; i < GROWS * (KCH / 4); i += 256) {
            const int r = i >> 5;
            const int c = (i & 31) * 4;
            *(float4*)&At[r][c] =
                *(const float4*)&X[(long)(row0 + r) * K + k0 + c];
        }
        __syncthreads();

        for (int k = 0; k < KCH; k += 4) {
            float4 a[RPT];
#pragma unroll
            for (int r = 0; r < RPT; ++r)
                a[r] = *(const float4*)&At[r0 + r][k];
#pragma unroll
            for (int ci = 0; ci < CPT; ++ci) {
                const float4 wv = *(const float4*)&W[(long)(c0 + ci) * K + k0 + k];
#pragma unroll
                for (int r = 0; r < RPT; ++r) {
                    acc[r][ci] = fmaf(a[r].x, wv.x, acc[r][ci]);
                    acc[r][ci] = fmaf(a[r].y, wv.y, acc[r][ci]);
                    acc[r][ci] = fmaf(a[r].z, wv.z, acc[r][ci]);
                    acc[r][ci] = fmaf(a[r].w, wv.w, acc[r][ci]);
                }
            }
        }
        __syncthreads();
    }

    // BN fold per column
    float s[CPT], sh[CPT], bias[CPT];
#pragma unroll
    for (int ci = 0; ci < CPT; ++ci) {
        const int c = c0 + ci;
        s[ci]    = g[c] * rsqrtf(v[c] + BN_EPS);
        sh[ci]   = beta[c] - m[c] * s[ci];
        bias[ci] = b[c];
    }

#pragma unroll
    for (int r = 0; r < RPT; ++r) {
        const int q = row0 + r0 + r;
        float y[CPT];
#pragma unroll
        for (int ci = 0; ci < CPT; ++ci) {
            float t = (acc[r][ci] + bias[ci]) * s[ci] + sh[ci];
            y[ci] = fmaxf(t, 0.f);
        }
        if (f2) {
            const float4 w4 = wts[q];
            const int4  i4 = idx[q];
            const float* fa = &f2[(long)i4.x * COUT + c0];
            const float* fb = &f2[(long)i4.y * COUT + c0];
            const float* fc = &f2[(long)i4.z * COUT + c0];
#pragma unroll
            for (int ci = 0; ci < CPT; ++ci)
                y[ci] += w4.x * fa[ci] + w4.y * fb[ci] + w4.z * fc[ci];
        }
        *(float4*)&out[(long)q * COUT + c0]     = make_float4(y[0], y[1], y[2], y[3]);
        *(float4*)&out[(long)q * COUT + c0 + 4] = make_float4(y[4], y[5], y[6], y[7]);
    }
}

// ---------------------------------------------------------------------------
// KNN phase 1: per-partition partial top-3. d2 replicates numpy/XLA f32
// arithmetic bit-exactly (see R4): qq/pp as separately-rounded squares with
// sequential adds; dot as fma chain from a rounded first product;
// d2 = fl(fl(qq+pp) - fl(2*dot)). Strict-< insertion => stable ties.
// ---------------------------------------------------------------------------
__global__ __launch_bounds__(256) void knn3_part_k(
    const float* __restrict__ P1, const float* __restrict__ P2,
    const int* __restrict__ rs1, const int* __restrict__ rs2, int B,
    float4* __restrict__ pd, int4* __restrict__ pi, int N1)
{
    __shared__ float4 Pt[4096 / NPART];   // 512 candidates, 8 KB

    const int tid   = threadIdx.x;
    const int qbase = blockIdx.x * QPB;
    const int part  = blockIdx.y;

    // segment of this block (uniform: QPB divides segment size)
    int seg = 0;
    while (seg + 1 < B && qbase >= rs1[seg + 1]) ++seg;
    const int pstart = rs2[seg];
    const int plen   = rs2[seg + 1] - pstart;
    const int cb = pstart + (int)(((long)plen * part) / NPART);
    const int ce = pstart + (int)(((long)plen * (part + 1)) / NPART);
    const int cnt = ce - cb;

    for (int i = tid; i < cnt; i += 256) {
        const float px = P2[(long)(cb + i) * 3 + 0];
        const float py = P2[(long)(cb + i) * 3 + 1];
        const float pz = P2[(long)(cb + i) * 3 + 2];
        const float pp = __fadd_rn(__fadd_rn(__fmul_rn(px, px), __fmul_rn(py, py)),
                                   __fmul_rn(pz, pz));
        Pt[i] = make_float4(px, py, pz, pp);
    }
    __syncthreads();

    float qx[QPT], qy[QPT], qz[QPT], qq[QPT];
    float b0[QPT], b1[QPT], b2[QPT];
    int   i0[QPT], i1[QPT], i2[QPT];
#pragma unroll
    for (int u = 0; u < QPT; ++u) {
        const int q = qbase + u * 256 + tid;
        qx[u] = P1[q * 3 + 0];
        qy[u] = P1[q * 3 + 1];
        qz[u] = P1[q * 3 + 2];
        qq[u] = __fadd_rn(__fadd_rn(__fmul_rn(qx[u], qx[u]), __fmul_rn(qy[u], qy[u])),
                          __fmul_rn(qz[u], qz[u]));
        b0[u] = 3.4e38f; b1[u] = 3.4e38f; b2[u] = 3.4e38f;
        i0[u] = cb; i1[u] = cb; i2[u] = cb;
    }

#pragma unroll 2
    for (int j = 0; j < cnt; ++j) {
        const float4 p = Pt[j];            // wave-uniform broadcast b128
        const int gj = cb + j;
#pragma unroll
        for (int u = 0; u < QPT; ++u) {
            const float dot = fmaf(qz[u], p.z, fmaf(qy[u], p.y, __fmul_rn(qx[u], p.x)));
            const float d2  = __fsub_rn(__fadd_rn(qq[u], p.w), __fmul_rn(2.0f, dot));
            if (d2 < b2[u]) {              // strict <: stable ties
                if (d2 < b1[u]) {
                    b2[u] = b1[u]; i2[u] = i1[u];
                    if (d2 < b0[u]) { b1[u] = b0[u]; i1[u] = i0[u]; b0[u] = d2; i0[u] = gj; }
                    else            { b1[u] = d2; i1[u] = gj; }
                } else { b2[u] = d2; i2[u] = gj; }
            }
        }
    }

#pragma unroll
    for (int u = 0; u < QPT; ++u) {
        const int q = qbase + u * 256 + tid;
        pd[(long)part * N1 + q] = make_float4(b0[u], b1[u], b2[u], 0.f);
        pi[(long)part * N1 + q] = make_int4(i0[u], i1[u], i2[u], 0);
    }
}

// ---------------------------------------------------------------------------
// KNN phase 2: merge NPART partial top-3 lists (inserted in ascending
// partition order => strict-< keeps np's stable ordering), then weights in
// exact np f32 arithmetic.
// ---------------------------------------------------------------------------
__global__ __launch_bounds__(256) void knn3_merge_k(
    const float4* __restrict__ pd, const int4* __restrict__ pi,
    float4* __restrict__ wts, int4* __restrict__ idxout, int N1)
{
    const int q = blockIdx.x * 256 + threadIdx.x;
    if (q >= N1) return;

    float b0 = 3.4e38f, b1 = 3.4e38f, b2 = 3.4e38f;
    int   i0 = 0, i1 = 0, i2 = 0;

    for (int p = 0; p < NPART; ++p) {
        const float4 d = pd[(long)p * N1 + q];
        const int4  ii = pi[(long)p * N1 + q];
        const float dv[3] = {d.x, d.y, d.z};
        const int   iv[3] = {ii.x, ii.y, ii.z};
#pragma unroll
        for (int t = 0; t < 3; ++t) {
            const float dt = dv[t];
            const int   it = iv[t];
            if (dt < b2) {
                if (dt < b1) {
                    b2 = b1; i2 = i1;
                    if (dt < b0) { b1 = b0; i1 = i0; b0 = dt; i0 = it; }
                    else         { b1 = dt; i1 = it; }
                } else { b2 = dt; i2 = it; }
            }
        }
    }

    const float d0 = fmaxf(b0, 0.f);
    const float d1 = fmaxf(b1, 0.f);
    const float d2v = fmaxf(b2, 0.f);
    const float w0 = __fdiv_rn(1.0f, __fadd_rn(d0, 1e-8f));
    const float w1 = __fdiv_rn(1.0f, __fadd_rn(d1, 1e-8f));
    const float w2 = __fdiv_rn(1.0f, __fadd_rn(d2v, 1e-8f));
    const float wsum = __fadd_rn(__fadd_rn(w0, w1), w2);
    wts[q]    = make_float4(__fdiv_rn(w0, wsum), __fdiv_rn(w1, wsum),
                            __fdiv_rn(w2, wsum), 0.f);
    idxout[q] = make_int4(i0, i1, i2, 0);
}

// ---------------------------------------------------------------------------
extern "C" void kernel_launch(void* const* d_in, const int* in_sizes, int n_in,
                              void* d_out, int out_size, void* d_ws, size_t ws_size,
                              hipStream_t stream) {
    const float* P1   = (const float*)d_in[0];
    const float* F1   = (const float*)d_in[1];
    const int*   rs1  = (const int*)  d_in[2];
    const float* P2   = (const float*)d_in[3];
    const float* F2in = (const float*)d_in[4];
    const int*   rs2  = (const int*)  d_in[5];
    const float* w1   = (const float*)d_in[6];
    const float* b1   = (const float*)d_in[7];
    const float* g1   = (const float*)d_in[8];
    const float* be1  = (const float*)d_in[9];
    const float* m1   = (const float*)d_in[10];
    const float* v1   = (const float*)d_in[11];
    const float* w2   = (const float*)d_in[12];
    const float* b2   = (const float*)d_in[13];
    const float* g2   = (const float*)d_in[14];
    const float* be2  = (const float*)d_in[15];
    const float* m2   = (const float*)d_in[16];
    const float* v2   = (const float*)d_in[17];

    const int N1  = in_sizes[0] / 3;      // 65536
    const int N2  = in_sizes[3] / 3;      // 16384
    const int CIN = in_sizes[4] / N2;     // 512
    const int B   = in_sizes[2] - 1;      // 4

    char* ws = (char*)d_ws;
    float*  f2  = (float*)ws;                         ws += (size_t)N2 * COUT * 4;   // 16.8 MB
    float4* wts = (float4*)ws;                        ws += (size_t)N1 * 16;         //  1 MB
    int4*   idx = (int4*)ws;                          ws += (size_t)N1 * 16;         //  1 MB
    float4* pd  = (float4*)ws;                        ws += (size_t)NPART * N1 * 16; //  8.4 MB
    int4*   pi  = (int4*)ws;                          /* 8.4 MB */

    // KNN partials: grid (query blocks) x (candidate partitions)
    knn3_part_k<<<dim3(N1 / QPB, NPART), 256, 0, stream>>>(
        P1, P2, rs1, rs2, B, pd, pi, N1);

    // merge partials -> weights/indices
    knn3_merge_k<<<(N1 + 255) / 256, 256, 0, stream>>>(pd, pi, wts, idx, N1);

    // f2 = relu(bn(feat_2 @ w2^T + b2))
    gemm_bn_relu_k<<<N2 / GROWS, 256, 0, stream>>>(
        F2in, w2, b2, g2, be2, m2, v2, f2, N2, CIN,
        nullptr, nullptr, nullptr);

    // out = relu(bn(feat_1 @ w1^T + b1)) + interp
    gemm_bn_relu_k<<<N1 / GROWS, 256, 0, stream>>>(
        F1, w1, b1, g1, be1, m1, v1, (float*)d_out, N1, COUT,
        f2, wts, idx);
}

// Round 6
// 524.192 us; speedup vs baseline: 2.1352x; 2.1352x over previous
//
#include <hip/hip_runtime.h>
#include <math.h>

#define BN_EPS 1e-5f
constexpr int COUT = 256;

// ---- KNN config ----
constexpr int QPT   = 2;                 // queries per thread
constexpr int NPART = 8;                 // candidate partitions
constexpr int QPB   = 256 * QPT;         // 512 queries per block

// ---- GEMM config: tile 128x128, TK=32, 256 threads, 8x8 per thread ----
constexpr int TK  = 32;
constexpr int LDT = 36;   // padded LDS row stride (floats): conflict-free reads

// ---------------------------------------------------------------------------
// GEMM out[M][256] = relu((X[M][K] @ W[256][K]^T + b)*s + sh) (+ 3NN gather)
// Both A and W tiles staged in LDS. Thread (tx=tid&15, ty=tid>>4) computes
// rows {ty+16i} x cols {ct0+tx+16j}, i,j=0..7. Spread assignment makes
// a-reads broadcast/conflict-free and b-reads 2-way (free).
// ---------------------------------------------------------------------------
__global__ __launch_bounds__(256) void gemm_bn_relu_k(
    const float* __restrict__ X, const float* __restrict__ W,
    const float* __restrict__ b, const float* __restrict__ g,
    const float* __restrict__ beta, const float* __restrict__ m,
    const float* __restrict__ v,
    float* __restrict__ out, int M, int K,
    const float* __restrict__ f2,      // nullable: interp source (N2 x 256)
    const float4* __restrict__ wts,
    const int4* __restrict__ idx)
{
    const int tid = threadIdx.x;
    const int tx  = tid & 15;
    const int ty  = tid >> 4;
    const int row0 = blockIdx.x * 128;
    const int ct0  = blockIdx.y * 128;

    __shared__ float As[128 * LDT];   // 18 KB
    __shared__ float Bs[128 * LDT];   // 18 KB

    float acc[8][8];
#pragma unroll
    for (int i = 0; i < 8; ++i)
#pragma unroll
        for (int j = 0; j < 8; ++j) acc[i][j] = 0.f;

    for (int k0 = 0; k0 < K; k0 += TK) {
        // stage A (128x32) and B (=W cols ct0..ct0+127, 128x32)
#pragma unroll
        for (int t = 0; t < 4; ++t) {
            const int i = tid + t * 256;
            const int r = i >> 3;
            const int kq = (i & 7) * 4;
            *(float4*)&As[r * LDT + kq] =
                *(const float4*)&X[(long)(row0 + r) * K + k0 + kq];
            *(float4*)&Bs[r * LDT + kq] =
                *(const float4*)&W[(long)(ct0 + r) * K + k0 + kq];
        }
        __syncthreads();

#pragma unroll
        for (int k4 = 0; k4 < TK; k4 += 4) {
            float4 av[8];
#pragma unroll
            for (int i = 0; i < 8; ++i)
                av[i] = *(const float4*)&As[(ty + 16 * i) * LDT + k4];
#pragma unroll
            for (int j = 0; j < 8; ++j) {
                const float4 bv = *(const float4*)&Bs[(tx + 16 * j) * LDT + k4];
#pragma unroll
                for (int i = 0; i < 8; ++i) {
                    acc[i][j] = fmaf(av[i].x, bv.x, acc[i][j]);
                    acc[i][j] = fmaf(av[i].y, bv.y, acc[i][j]);
                    acc[i][j] = fmaf(av[i].z, bv.z, acc[i][j]);
                    acc[i][j] = fmaf(av[i].w, bv.w, acc[i][j]);
                }
            }
        }
        __syncthreads();
    }

    // BN fold per col
    float s[8], sh[8], bi[8];
#pragma unroll
    for (int j = 0; j < 8; ++j) {
        const int c = ct0 + tx + 16 * j;
        s[j]  = g[c] * rsqrtf(v[c] + BN_EPS);
        sh[j] = beta[c] - m[c] * s[j];
        bi[j] = b[c];
    }

#pragma unroll
    for (int i = 0; i < 8; ++i) {
        const int q = row0 + ty + 16 * i;
        float y[8];
#pragma unroll
        for (int j = 0; j < 8; ++j)
            y[j] = fmaxf((acc[i][j] + bi[j]) * s[j] + sh[j], 0.f);
        if (f2) {
            const float4 w4 = wts[q];
            const int4  i4 = idx[q];
            const float* fa = f2 + (long)i4.x * COUT + ct0 + tx;
            const float* fb = f2 + (long)i4.y * COUT + ct0 + tx;
            const float* fc = f2 + (long)i4.z * COUT + ct0 + tx;
#pragma unroll
            for (int j = 0; j < 8; ++j)
                y[j] += w4.x * fa[16 * j] + w4.y * fb[16 * j] + w4.z * fc[16 * j];
        }
#pragma unroll
        for (int j = 0; j < 8; ++j)
            out[(long)q * COUT + ct0 + tx + 16 * j] = y[j];
    }
}

// ---------------------------------------------------------------------------
// KNN phase 1: per-partition partial top-3, BRANCHLESS inner loop.
// d2 replicates numpy f32 arithmetic bit-exactly (verified R4):
//   qq/pp: separately-rounded squares, sequential adds;
//   dot:   fma chain from rounded first product (sgemm K=3);
//   d2 =   fl(fl(qq+pp) - fl(2*dot)).
// Strict-< => stable (lowest-index) ties; min/max keep exact values.
// ---------------------------------------------------------------------------
__global__ __launch_bounds__(256) void knn3_part_k(
    const float* __restrict__ P1, const float* __restrict__ P2,
    const int* __restrict__ rs1, const int* __restrict__ rs2, int B,
    float4* __restrict__ pd, int4* __restrict__ pi, int N1)
{
    __shared__ float4 Pt[4096 / NPART];   // 512 candidates, 8 KB

    const int tid   = threadIdx.x;
    const int qbase = blockIdx.x * QPB;
    const int part  = blockIdx.y;

    int seg = 0;
    while (seg + 1 < B && qbase >= rs1[seg + 1]) ++seg;
    const int pstart = rs2[seg];
    const int plen   = rs2[seg + 1] - pstart;
    const int cb = pstart + (int)(((long)plen * part) / NPART);
    const int ce = pstart + (int)(((long)plen * (part + 1)) / NPART);
    const int cnt = ce - cb;

    for (int i = tid; i < cnt; i += 256) {
        const float px = P2[(long)(cb + i) * 3 + 0];
        const float py = P2[(long)(cb + i) * 3 + 1];
        const float pz = P2[(long)(cb + i) * 3 + 2];
        const float pp = __fadd_rn(__fadd_rn(__fmul_rn(px, px), __fmul_rn(py, py)),
                                   __fmul_rn(pz, pz));
        Pt[i] = make_float4(px, py, pz, pp);
    }
    __syncthreads();

    float qx[QPT], qy[QPT], qz[QPT], qq[QPT];
    float b0[QPT], b1[QPT], b2[QPT];
    int   i0[QPT], i1[QPT], i2[QPT];
#pragma unroll
    for (int u = 0; u < QPT; ++u) {
        const int q = qbase + u * 256 + tid;
        qx[u] = P1[q * 3 + 0];
        qy[u] = P1[q * 3 + 1];
        qz[u] = P1[q * 3 + 2];
        qq[u] = __fadd_rn(__fadd_rn(__fmul_rn(qx[u], qx[u]), __fmul_rn(qy[u], qy[u])),
                          __fmul_rn(qz[u], qz[u]));
        b0[u] = 3.4e38f; b1[u] = 3.4e38f; b2[u] = 3.4e38f;
        i0[u] = cb; i1[u] = cb; i2[u] = cb;
    }

#pragma unroll 4
    for (int j = 0; j < cnt; ++j) {
        const float4 p = Pt[j];            // wave-uniform broadcast
        const int gj = cb + j;
#pragma unroll
        for (int u = 0; u < QPT; ++u) {
            const float dot = fmaf(qz[u], p.z, fmaf(qy[u], p.y, __fmul_rn(qx[u], p.x)));
            const float d2  = __fsub_rn(__fadd_rn(qq[u], p.w), __fmul_rn(2.0f, dot));
            // branchless 3-smallest insert (strict <, exact values kept)
            const bool lt0 = d2 < b0[u];
            const bool lt1 = d2 < b1[u];
            const bool lt2 = d2 < b2[u];
            const float t1 = fmaxf(d2, b0[u]);
            const float t2 = fmaxf(d2, b1[u]);
            i2[u] = lt1 ? i1[u] : (lt2 ? gj : i2[u]);
            i1[u] = lt0 ? i0[u] : (lt1 ? gj : i1[u]);
            i0[u] = lt0 ? gj : i0[u];
            b0[u] = fminf(b0[u], d2);
            b1[u] = fminf(b1[u], t1);
            b2[u] = fminf(b2[u], t2);
        }
    }

#pragma unroll
    for (int u = 0; u < QPT; ++u) {
        const int q = qbase + u * 256 + tid;
        pd[(long)part * N1 + q] = make_float4(b0[u], b1[u], b2[u], 0.f);
        pi[(long)part * N1 + q] = make_int4(i0[u], i1[u], i2[u], 0);
    }
}

// ---------------------------------------------------------------------------
// KNN phase 2: merge NPART partials (ascending partition order => stable).
// ---------------------------------------------------------------------------
__global__ __launch_bounds__(256) void knn3_merge_k(
    const float4* __restrict__ pd, const int4* __restrict__ pi,
    float4* __restrict__ wts, int4* __restrict__ idxout, int N1)
{
    const int q = blockIdx.x * 256 + threadIdx.x;
    if (q >= N1) return;

    float b0 = 3.4e38f, b1 = 3.4e38f, b2 = 3.4e38f;
    int   i0 = 0, i1 = 0, i2 = 0;

    for (int p = 0; p < NPART; ++p) {
        const float4 d = pd[(long)p * N1 + q];
        const int4  ii = pi[(long)p * N1 + q];
        const float dv[3] = {d.x, d.y, d.z};
        const int   iv[3] = {ii.x, ii.y, ii.z};
#pragma unroll
        for (int t = 0; t < 3; ++t) {
            const float dt = dv[t];
            const int   it = iv[t];
            const bool lt0 = dt < b0;
            const bool lt1 = dt < b1;
            const bool lt2 = dt < b2;
            const float t1 = fmaxf(dt, b0);
            const float t2 = fmaxf(dt, b1);
            i2 = lt1 ? i1 : (lt2 ? it : i2);
            i1 = lt0 ? i0 : (lt1 ? it : i1);
            i0 = lt0 ? it : i0;
            b0 = fminf(b0, dt);
            b1 = fminf(b1, t1);
            b2 = fminf(b2, t2);
        }
    }

    const float d0 = fmaxf(b0, 0.f);
    const float d1 = fmaxf(b1, 0.f);
    const float d2v = fmaxf(b2, 0.f);
    const float w0 = __fdiv_rn(1.0f, __fadd_rn(d0, 1e-8f));
    const float w1 = __fdiv_rn(1.0f, __fadd_rn(d1, 1e-8f));
    const float w2 = __fdiv_rn(1.0f, __fadd_rn(d2v, 1e-8f));
    const float wsum = __fadd_rn(__fadd_rn(w0, w1), w2);
    wts[q]    = make_float4(__fdiv_rn(w0, wsum), __fdiv_rn(w1, wsum),
                            __fdiv_rn(w2, wsum), 0.f);
    idxout[q] = make_int4(i0, i1, i2, 0);
}

// ---------------------------------------------------------------------------
extern "C" void kernel_launch(void* const* d_in, const int* in_sizes, int n_in,
                              void* d_out, int out_size, void* d_ws, size_t ws_size,
                              hipStream_t stream) {
    const float* P1   = (const float*)d_in[0];
    const float* F1   = (const float*)d_in[1];
    const int*   rs1  = (const int*)  d_in[2];
    const float* P2   = (const float*)d_in[3];
    const float* F2in = (const float*)d_in[4];
    const int*   rs2  = (const int*)  d_in[5];
    const float* w1   = (const float*)d_in[6];
    const float* b1   = (const float*)d_in[7];
    const float* g1   = (const float*)d_in[8];
    const float* be1  = (const float*)d_in[9];
    const float* m1   = (const float*)d_in[10];
    const float* v1   = (const float*)d_in[11];
    const float* w2   = (const float*)d_in[12];
    const float* b2   = (const float*)d_in[13];
    const float* g2   = (const float*)d_in[14];
    const float* be2  = (const float*)d_in[15];
    const float* m2   = (const float*)d_in[16];
    const float* v2   = (const float*)d_in[17];

    const int N1  = in_sizes[0] / 3;      // 65536
    const int N2  = in_sizes[3] / 3;      // 16384
    const int CIN = in_sizes[4] / N2;     // 512
    const int B   = in_sizes[2] - 1;      // 4

    char* ws = (char*)d_ws;
    float*  f2  = (float*)ws;   ws += (size_t)N2 * COUT * 4;    // 16.8 MB
    float4* wts = (float4*)ws;  ws += (size_t)N1 * 16;          //  1 MB
    int4*   idx = (int4*)ws;    ws += (size_t)N1 * 16;          //  1 MB
    float4* pd  = (float4*)ws;  ws += (size_t)NPART * N1 * 16;  //  8.4 MB
    int4*   pi  = (int4*)ws;                                    //  8.4 MB

    knn3_part_k<<<dim3(N1 / QPB, NPART), 256, 0, stream>>>(
        P1, P2, rs1, rs2, B, pd, pi, N1);

    knn3_merge_k<<<(N1 + 255) / 256, 256, 0, stream>>>(pd, pi, wts, idx, N1);

    // f2 = relu(bn(feat_2 @ w2^T + b2))
    gemm_bn_relu_k<<<dim3(N2 / 128, 2), 256, 0, stream>>>(
        F2in, w2, b2, g2, be2, m2, v2, f2, N2, CIN,
        nullptr, nullptr, nullptr);

    // out = relu(bn(feat_1 @ w1^T + b1)) + interp
    gemm_bn_relu_k<<<dim3(N1 / 128, 2), 256, 0, stream>>>(
        F1, w1, b1, g1, be1, m1, v1, (float*)d_out, N1, COUT,
        f2, wts, idx);
}

// Round 7
// 476.978 us; speedup vs baseline: 2.3466x; 1.0990x over previous
//
#include <hip/hip_runtime.h>
#include <hip/hip_bf16.h>
#include <math.h>

#define BN_EPS 1e-5f
constexpr int COUT = 256;

typedef __attribute__((ext_vector_type(8))) short short8;
typedef __attribute__((ext_vector_type(4))) float floatx4;

// ---- KNN config ----
constexpr int QPT   = 4;                 // queries per thread
constexpr int NPART = 8;                 // candidate partitions
constexpr int QPB   = 256 * QPT;         // 1024 queries per block

// ---- MFMA GEMM config: 128x128 tile, BK=32, 4 waves (2x2), 64x64/wave ----
constexpr int BM = 128;
constexpr int BNT = 128;
constexpr int BK = 32;
constexpr int SA = 40;   // LDS row stride in bf16 elems: (5r+g)%8 -> 2-way free

__device__ inline unsigned short bf16_rn(float x) {
    __hip_bfloat16 h = __float2bfloat16(x);
    return *reinterpret_cast<unsigned short*>(&h);
}
__device__ inline float bf16_f(unsigned short u) {
    unsigned int v = ((unsigned int)u) << 16;
    float f;
    __builtin_memcpy(&f, &v, 4);
    return f;
}

// ---------------------------------------------------------------------------
// W (f32, row-major [256][K]) -> bf16 bits
// ---------------------------------------------------------------------------
__global__ __launch_bounds__(256) void cvt_w_k(const float* __restrict__ W,
                                               unsigned short* __restrict__ Wb,
                                               int n) {
    const int i = blockIdx.x * 256 + threadIdx.x;
    if (i < n) Wb[i] = bf16_rn(W[i]);
}

// ---------------------------------------------------------------------------
// MFMA GEMM: out[M][256] = relu((X @ Wbf^T + b)*s + sh) (+ 3NN gather).
// A split on the fly: X = hi + lo (both bf16); W pre-rounded bf16.
// out = (A_hi + A_lo) . Wbf^T  (2 MFMAs per frag pair, shared B-frag).
// Frag maps (m89/m91-verified): A row=lane&15,k=(lane>>4)*8+e; B col=lane&15,
// same k; D col=lane&15,row=(lane>>4)*4+reg.
// ---------------------------------------------------------------------------
__global__ __launch_bounds__(256) void gemm_mfma_k(
    const float* __restrict__ X, const unsigned short* __restrict__ Wb,
    const float* __restrict__ b, const float* __restrict__ g,
    const float* __restrict__ beta, const float* __restrict__ m,
    const float* __restrict__ v,
    float* __restrict__ out, int M, int K,
    const float* __restrict__ f2,
    const float4* __restrict__ wts,
    const int4* __restrict__ idx)
{
    __shared__ unsigned short Ahi[BM * SA];   // 10 KB
    __shared__ unsigned short Alo[BM * SA];   // 10 KB
    __shared__ unsigned short Bs [BNT * SA];  // 10 KB

    const int tid  = threadIdx.x;
    const int lane = tid & 63;
    const int wid  = tid >> 6;
    const int wr   = wid >> 1;       // wave row (0..1)
    const int wc   = wid & 1;        // wave col (0..1)
    const int rl   = lane & 15;
    const int kg   = (lane >> 4) * 8;
    const int row0 = blockIdx.x * BM;
    const int ct0  = blockIdx.y * BNT;

    floatx4 acc[4][4];
#pragma unroll
    for (int i = 0; i < 4; ++i)
#pragma unroll
        for (int j = 0; j < 4; ++j) acc[i][j] = (floatx4){0.f, 0.f, 0.f, 0.f};

    for (int k0 = 0; k0 < K; k0 += BK) {
        // ---- stage A (128x32 f32 -> hi/lo bf16) ----
#pragma unroll
        for (int p = 0; p < 4; ++p) {
            const int i = tid + p * 256;      // 1024 float4 chunks
            const int r = i >> 3;
            const int c = (i & 7) * 4;
            const float4 xv = *(const float4*)&X[(long)(row0 + r) * K + k0 + c];
            const unsigned short h0 = bf16_rn(xv.x), h1 = bf16_rn(xv.y),
                                 h2 = bf16_rn(xv.z), h3 = bf16_rn(xv.w);
            const unsigned short l0 = bf16_rn(xv.x - bf16_f(h0)),
                                 l1 = bf16_rn(xv.y - bf16_f(h1)),
                                 l2 = bf16_rn(xv.z - bf16_f(h2)),
                                 l3 = bf16_rn(xv.w - bf16_f(h3));
            uint2 hp, lp;
            hp.x = (unsigned)h0 | ((unsigned)h1 << 16);
            hp.y = (unsigned)h2 | ((unsigned)h3 << 16);
            lp.x = (unsigned)l0 | ((unsigned)l1 << 16);
            lp.y = (unsigned)l2 | ((unsigned)l3 << 16);
            *(uint2*)&Ahi[r * SA + c] = hp;
            *(uint2*)&Alo[r * SA + c] = lp;
        }
        // ---- stage B (128x32 bf16 from global) ----
#pragma unroll
        for (int p = 0; p < 2; ++p) {
            const int i = tid + p * 256;      // 512 chunks of 8 ushort
            const int r = i >> 2;
            const int c = (i & 3) * 8;
            const short8 wv = *(const short8*)&Wb[(long)(ct0 + r) * K + k0 + c];
            *(short8*)&Bs[r * SA + c] = wv;
        }
        __syncthreads();

        short8 ah[4], al[4];
#pragma unroll
        for (int i = 0; i < 4; ++i) {
            const int r = wr * 64 + i * 16 + rl;
            ah[i] = *(const short8*)&Ahi[r * SA + kg];
            al[i] = *(const short8*)&Alo[r * SA + kg];
        }
#pragma unroll
        for (int j = 0; j < 4; ++j) {
            const int c = wc * 64 + j * 16 + rl;
            const short8 bv = *(const short8*)&Bs[c * SA + kg];
#pragma unroll
            for (int i = 0; i < 4; ++i) {
                acc[i][j] = __builtin_amdgcn_mfma_f32_16x16x32_bf16(
                    ah[i], bv, acc[i][j], 0, 0, 0);
                acc[i][j] = __builtin_amdgcn_mfma_f32_16x16x32_bf16(
                    al[i], bv, acc[i][j], 0, 0, 0);
            }
        }
        __syncthreads();
    }

    // ---- epilogue: BN + relu (+ gather) ----
    float s[4], sh[4], bi[4];
    int   cc[4];
#pragma unroll
    for (int j = 0; j < 4; ++j) {
        const int c = ct0 + wc * 64 + j * 16 + rl;
        cc[j] = c;
        s[j]  = g[c] * rsqrtf(v[c] + BN_EPS);
        sh[j] = beta[c] - m[c] * s[j];
        bi[j] = b[c];
    }
    const int rq = lane >> 4;
#pragma unroll
    for (int i = 0; i < 4; ++i) {
#pragma unroll
        for (int r = 0; r < 4; ++r) {
            const int q = row0 + wr * 64 + i * 16 + rq * 4 + r;
            float4 w4;
            int4   i4;
            if (f2) { w4 = wts[q]; i4 = idx[q]; }
#pragma unroll
            for (int j = 0; j < 4; ++j) {
                float y = (acc[i][j][r] + bi[j]) * s[j] + sh[j];
                y = fmaxf(y, 0.f);
                if (f2) {
                    y += w4.x * f2[(long)i4.x * COUT + cc[j]]
                       + w4.y * f2[(long)i4.y * COUT + cc[j]]
                       + w4.z * f2[(long)i4.z * COUT + cc[j]];
                }
                out[(long)q * COUT + cc[j]] = y;
            }
        }
    }
}

// ---------------------------------------------------------------------------
// KNN phase 1: per-partition partial top-3, branchless, QPT=4 streams.
// d2 replicates numpy f32 arithmetic bit-exactly (verified R4).
// ---------------------------------------------------------------------------
__global__ __launch_bounds__(256) void knn3_part_k(
    const float* __restrict__ P1, const float* __restrict__ P2,
    const int* __restrict__ rs1, const int* __restrict__ rs2, int B,
    float4* __restrict__ pd, int4* __restrict__ pi, int N1)
{
    __shared__ float4 Pt[4096 / NPART];   // 512 candidates, 8 KB

    const int tid   = threadIdx.x;
    const int qbase = blockIdx.x * QPB;
    const int part  = blockIdx.y;

    int seg = 0;
    while (seg + 1 < B && qbase >= rs1[seg + 1]) ++seg;
    const int pstart = rs2[seg];
    const int plen   = rs2[seg + 1] - pstart;
    const int cb = pstart + (int)(((long)plen * part) / NPART);
    const int ce = pstart + (int)(((long)plen * (part + 1)) / NPART);
    const int cnt = ce - cb;

    for (int i = tid; i < cnt; i += 256) {
        const float px = P2[(long)(cb + i) * 3 + 0];
        const float py = P2[(long)(cb + i) * 3 + 1];
        const float pz = P2[(long)(cb + i) * 3 + 2];
        const float pp = __fadd_rn(__fadd_rn(__fmul_rn(px, px), __fmul_rn(py, py)),
                                   __fmul_rn(pz, pz));
        Pt[i] = make_float4(px, py, pz, pp);
    }
    __syncthreads();

    float qx[QPT], qy[QPT], qz[QPT], qq[QPT];
    float b0[QPT], b1[QPT], b2[QPT];
    int   i0[QPT], i1[QPT], i2[QPT];
#pragma unroll
    for (int u = 0; u < QPT; ++u) {
        const int q = qbase + u * 256 + tid;
        qx[u] = P1[q * 3 + 0];
        qy[u] = P1[q * 3 + 1];
        qz[u] = P1[q * 3 + 2];
        qq[u] = __fadd_rn(__fadd_rn(__fmul_rn(qx[u], qx[u]), __fmul_rn(qy[u], qy[u])),
                          __fmul_rn(qz[u], qz[u]));
        b0[u] = 3.4e38f; b1[u] = 3.4e38f; b2[u] = 3.4e38f;
        i0[u] = cb; i1[u] = cb; i2[u] = cb;
    }

#pragma unroll 2
    for (int j = 0; j < cnt; ++j) {
        const float4 p = Pt[j];            // wave-uniform broadcast
        const int gj = cb + j;
#pragma unroll
        for (int u = 0; u < QPT; ++u) {
            const float dot = fmaf(qz[u], p.z, fmaf(qy[u], p.y, __fmul_rn(qx[u], p.x)));
            const float d2  = __fsub_rn(__fadd_rn(qq[u], p.w), __fmul_rn(2.0f, dot));
            const bool lt0 = d2 < b0[u];
            const bool lt1 = d2 < b1[u];
            const bool lt2 = d2 < b2[u];
            const float t1 = fmaxf(d2, b0[u]);
            const float t2 = fmaxf(d2, b1[u]);
            i2[u] = lt1 ? i1[u] : (lt2 ? gj : i2[u]);
            i1[u] = lt0 ? i0[u] : (lt1 ? gj : i1[u]);
            i0[u] = lt0 ? gj : i0[u];
            b0[u] = fminf(b0[u], d2);
            b1[u] = fminf(b1[u], t1);
            b2[u] = fminf(b2[u], t2);
        }
    }

#pragma unroll
    for (int u = 0; u < QPT; ++u) {
        const int q = qbase + u * 256 + tid;
        pd[(long)part * N1 + q] = make_float4(b0[u], b1[u], b2[u], 0.f);
        pi[(long)part * N1 + q] = make_int4(i0[u], i1[u], i2[u], 0);
    }
}

// ---------------------------------------------------------------------------
// KNN phase 2: merge NPART partials (ascending partition order => stable).
// ---------------------------------------------------------------------------
__global__ __launch_bounds__(256) void knn3_merge_k(
    const float4* __restrict__ pd, const int4* __restrict__ pi,
    float4* __restrict__ wts, int4* __restrict__ idxout, int N1)
{
    const int q = blockIdx.x * 256 + threadIdx.x;
    if (q >= N1) return;

    float b0 = 3.4e38f, b1 = 3.4e38f, b2 = 3.4e38f;
    int   i0 = 0, i1 = 0, i2 = 0;

    for (int p = 0; p < NPART; ++p) {
        const float4 d = pd[(long)p * N1 + q];
        const int4  ii = pi[(long)p * N1 + q];
        const float dv[3] = {d.x, d.y, d.z};
        const int   iv[3] = {ii.x, ii.y, ii.z};
#pragma unroll
        for (int t = 0; t < 3; ++t) {
            const float dt = dv[t];
            const int   it = iv[t];
            const bool lt0 = dt < b0;
            const bool lt1 = dt < b1;
            const bool lt2 = dt < b2;
            const float t1 = fmaxf(dt, b0);
            const float t2 = fmaxf(dt, b1);
            i2 = lt1 ? i1 : (lt2 ? it : i2);
            i1 = lt0 ? i0 : (lt1 ? it : i1);
            i0 = lt0 ? it : i0;
            b0 = fminf(b0, dt);
            b1 = fminf(b1, t1);
            b2 = fminf(b2, t2);
        }
    }

    const float d0 = fmaxf(b0, 0.f);
    const float d1 = fmaxf(b1, 0.f);
    const float d2v = fmaxf(b2, 0.f);
    const float w0 = __fdiv_rn(1.0f, __fadd_rn(d0, 1e-8f));
    const float w1 = __fdiv_rn(1.0f, __fadd_rn(d1, 1e-8f));
    const float w2 = __fdiv_rn(1.0f, __fadd_rn(d2v, 1e-8f));
    const float wsum = __fadd_rn(__fadd_rn(w0, w1), w2);
    wts[q]    = make_float4(__fdiv_rn(w0, wsum), __fdiv_rn(w1, wsum),
                            __fdiv_rn(w2, wsum), 0.f);
    idxout[q] = make_int4(i0, i1, i2, 0);
}

// ---------------------------------------------------------------------------
extern "C" void kernel_launch(void* const* d_in, const int* in_sizes, int n_in,
                              void* d_out, int out_size, void* d_ws, size_t ws_size,
                              hipStream_t stream) {
    const float* P1   = (const float*)d_in[0];
    const float* F1   = (const float*)d_in[1];
    const int*   rs1  = (const int*)  d_in[2];
    const float* P2   = (const float*)d_in[3];
    const float* F2in = (const float*)d_in[4];
    const int*   rs2  = (const int*)  d_in[5];
    const float* w1   = (const float*)d_in[6];
    const float* b1   = (const float*)d_in[7];
    const float* g1   = (const float*)d_in[8];
    const float* be1  = (const float*)d_in[9];
    const float* m1   = (const float*)d_in[10];
    const float* v1   = (const float*)d_in[11];
    const float* w2   = (const float*)d_in[12];
    const float* b2   = (const float*)d_in[13];
    const float* g2   = (const float*)d_in[14];
    const float* be2  = (const float*)d_in[15];
    const float* m2   = (const float*)d_in[16];
    const float* v2   = (const float*)d_in[17];

    const int N1  = in_sizes[0] / 3;      // 65536
    const int N2  = in_sizes[3] / 3;      // 16384
    const int CIN = in_sizes[4] / N2;     // 512
    const int B   = in_sizes[2] - 1;      // 4

    char* ws = (char*)d_ws;
    float*  f2  = (float*)ws;   ws += (size_t)N2 * COUT * 4;    // 16.8 MB
    float4* wts = (float4*)ws;  ws += (size_t)N1 * 16;          //  1 MB
    int4*   idx = (int4*)ws;    ws += (size_t)N1 * 16;          //  1 MB
    float4* pd  = (float4*)ws;  ws += (size_t)NPART * N1 * 16;  //  8.4 MB
    int4*   pi  = (int4*)ws;    ws += (size_t)NPART * N1 * 16;  //  8.4 MB
    unsigned short* wb1 = (unsigned short*)ws; ws += (size_t)COUT * COUT * 2; // 128 KB
    unsigned short* wb2 = (unsigned short*)ws;                  // 256 KB

    // weights -> bf16 (once per launch; tiny)
    cvt_w_k<<<(COUT * COUT + 255) / 256, 256, 0, stream>>>(w1, wb1, COUT * COUT);
    cvt_w_k<<<(COUT * CIN + 255) / 256, 256, 0, stream>>>(w2, wb2, COUT * CIN);

    knn3_part_k<<<dim3(N1 / QPB, NPART), 256, 0, stream>>>(
        P1, P2, rs1, rs2, B, pd, pi, N1);

    knn3_merge_k<<<(N1 + 255) / 256, 256, 0, stream>>>(pd, pi, wts, idx, N1);

    // f2 = relu(bn(feat_2 @ w2^T + b2))
    gemm_mfma_k<<<dim3(N2 / BM, COUT / BNT), 256, 0, stream>>>(
        F2in, wb2, b2, g2, be2, m2, v2, f2, N2, CIN,
        nullptr, nullptr, nullptr);

    // out = relu(bn(feat_1 @ w1^T + b1)) + interp
    gemm_mfma_k<<<dim3(N1 / BM, COUT / BNT), 256, 0, stream>>>(
        F1, wb1, b1, g1, be1, m1, v1, (float*)d_out, N1, COUT,
        f2, wts, idx);
}

// Round 8
// 401.126 us; speedup vs baseline: 2.7903x; 1.1891x over previous
//
#include <hip/hip_runtime.h>
#include <hip/hip_bf16.h>
#include <math.h>

#define BN_EPS 1e-5f
constexpr int COUT = 256;

typedef __attribute__((ext_vector_type(8))) short short8;
typedef __attribute__((ext_vector_type(4))) float floatx4;

// ---- KNN config ----
constexpr int QPT   = 4;                 // queries per thread
constexpr int NPART = 16;                // candidate partitions
constexpr int QPB   = 256 * QPT;         // 1024 queries per block

// ---- MFMA GEMM config: 128x128 tile, BK=32, 4 waves (2x2), 64x64/wave ----
constexpr int BM = 128;
constexpr int BNT = 128;
constexpr int BK = 32;
constexpr int SA = 40;   // LDS row stride in bf16 elems

__device__ inline unsigned short bf16_rn(float x) {
    __hip_bfloat16 h = __float2bfloat16(x);
    return *reinterpret_cast<unsigned short*>(&h);
}
__device__ inline float bf16_f(unsigned short u) {
    unsigned int v = ((unsigned int)u) << 16;
    float f;
    __builtin_memcpy(&f, &v, 4);
    return f;
}

// ---------------------------------------------------------------------------
__global__ __launch_bounds__(256) void cvt_w_k(const float* __restrict__ W,
                                               unsigned short* __restrict__ Wb,
                                               int n) {
    const int i = blockIdx.x * 256 + threadIdx.x;
    if (i < n) Wb[i] = bf16_rn(W[i]);
}

// ---------------------------------------------------------------------------
// MFMA GEMM: out[M][256] = relu((X @ Wbf^T + b)*s + sh) (+ 3NN gather).
// A split on the fly: X = hi + lo (both bf16); W pre-rounded bf16.
// ---------------------------------------------------------------------------
__global__ __launch_bounds__(256) void gemm_mfma_k(
    const float* __restrict__ X, const unsigned short* __restrict__ Wb,
    const float* __restrict__ b, const float* __restrict__ g,
    const float* __restrict__ beta, const float* __restrict__ m,
    const float* __restrict__ v,
    float* __restrict__ out, int M, int K,
    const float* __restrict__ f2,
    const float4* __restrict__ wts,
    const int4* __restrict__ idx)
{
    __shared__ unsigned short Ahi[BM * SA];
    __shared__ unsigned short Alo[BM * SA];
    __shared__ unsigned short Bs [BNT * SA];

    const int tid  = threadIdx.x;
    const int lane = tid & 63;
    const int wid  = tid >> 6;
    const int wr   = wid >> 1;
    const int wc   = wid & 1;
    const int rl   = lane & 15;
    const int kg   = (lane >> 4) * 8;
    const int row0 = blockIdx.x * BM;
    const int ct0  = blockIdx.y * BNT;

    floatx4 acc[4][4];
#pragma unroll
    for (int i = 0; i < 4; ++i)
#pragma unroll
        for (int j = 0; j < 4; ++j) acc[i][j] = (floatx4){0.f, 0.f, 0.f, 0.f};

    for (int k0 = 0; k0 < K; k0 += BK) {
#pragma unroll
        for (int p = 0; p < 4; ++p) {
            const int i = tid + p * 256;
            const int r = i >> 3;
            const int c = (i & 7) * 4;
            const float4 xv = *(const float4*)&X[(long)(row0 + r) * K + k0 + c];
            const unsigned short h0 = bf16_rn(xv.x), h1 = bf16_rn(xv.y),
                                 h2 = bf16_rn(xv.z), h3 = bf16_rn(xv.w);
            const unsigned short l0 = bf16_rn(xv.x - bf16_f(h0)),
                                 l1 = bf16_rn(xv.y - bf16_f(h1)),
                                 l2 = bf16_rn(xv.z - bf16_f(h2)),
                                 l3 = bf16_rn(xv.w - bf16_f(h3));
            uint2 hp, lp;
            hp.x = (unsigned)h0 | ((unsigned)h1 << 16);
            hp.y = (unsigned)h2 | ((unsigned)h3 << 16);
            lp.x = (unsigned)l0 | ((unsigned)l1 << 16);
            lp.y = (unsigned)l2 | ((unsigned)l3 << 16);
            *(uint2*)&Ahi[r * SA + c] = hp;
            *(uint2*)&Alo[r * SA + c] = lp;
        }
#pragma unroll
        for (int p = 0; p < 2; ++p) {
            const int i = tid + p * 256;
            const int r = i >> 2;
            const int c = (i & 3) * 8;
            const short8 wv = *(const short8*)&Wb[(long)(ct0 + r) * K + k0 + c];
            *(short8*)&Bs[r * SA + c] = wv;
        }
        __syncthreads();

        short8 ah[4], al[4];
#pragma unroll
        for (int i = 0; i < 4; ++i) {
            const int r = wr * 64 + i * 16 + rl;
            ah[i] = *(const short8*)&Ahi[r * SA + kg];
            al[i] = *(const short8*)&Alo[r * SA + kg];
        }
#pragma unroll
        for (int j = 0; j < 4; ++j) {
            const int c = wc * 64 + j * 16 + rl;
            const short8 bv = *(const short8*)&Bs[c * SA + kg];
#pragma unroll
            for (int i = 0; i < 4; ++i) {
                acc[i][j] = __builtin_amdgcn_mfma_f32_16x16x32_bf16(
                    ah[i], bv, acc[i][j], 0, 0, 0);
                acc[i][j] = __builtin_amdgcn_mfma_f32_16x16x32_bf16(
                    al[i], bv, acc[i][j], 0, 0, 0);
            }
        }
        __syncthreads();
    }

    float s[4], sh[4], bi[4];
    int   cc[4];
#pragma unroll
    for (int j = 0; j < 4; ++j) {
        const int c = ct0 + wc * 64 + j * 16 + rl;
        cc[j] = c;
        s[j]  = g[c] * rsqrtf(v[c] + BN_EPS);
        sh[j] = beta[c] - m[c] * s[j];
        bi[j] = b[c];
    }
    const int rq = lane >> 4;
#pragma unroll
    for (int i = 0; i < 4; ++i) {
#pragma unroll
        for (int r = 0; r < 4; ++r) {
            const int q = row0 + wr * 64 + i * 16 + rq * 4 + r;
            float4 w4;
            int4   i4;
            if (f2) { w4 = wts[q]; i4 = idx[q]; }
#pragma unroll
            for (int j = 0; j < 4; ++j) {
                float y = (acc[i][j][r] + bi[j]) * s[j] + sh[j];
                y = fmaxf(y, 0.f);
                if (f2) {
                    y += w4.x * f2[(long)i4.x * COUT + cc[j]]
                       + w4.y * f2[(long)i4.y * COUT + cc[j]]
                       + w4.z * f2[(long)i4.z * COUT + cc[j]];
                }
                out[(long)q * COUT + cc[j]] = y;
            }
        }
    }
}

// ---------------------------------------------------------------------------
// KNN phase 1: per-partition partial top-3, branchless, QPT=4, NPART=16.
// d2 bit-exact vs numpy f32 (verified R4):
//   pp   = fl(fl(fl(px^2)+fl(py^2))+fl(pz^2))      (from ORIGINAL coords)
//   dot2 = fmaf(qz,2pz, fmaf(qy,2py, fl(qx*2px)))  == fl(2*dot) exactly
//          (scaling by 2 commutes with RN rounding through the fma chain)
//   d2   = fl(fl(qq+pp) - dot2)
// Value update via min/med3 (== sequential 3-insert, proved for all
// orderings incl. ties; no NaNs possible). Strict-< index updates => stable.
// ---------------------------------------------------------------------------
__global__ __launch_bounds__(256) void knn3_part_k(
    const float* __restrict__ P1, const float* __restrict__ P2,
    const int* __restrict__ rs1, const int* __restrict__ rs2, int B,
    float4* __restrict__ pd, int4* __restrict__ pi, int N1)
{
    __shared__ float4 Pt[4096 / NPART];   // 256 candidates, 4 KB

    const int tid   = threadIdx.x;
    const int qbase = blockIdx.x * QPB;
    const int part  = blockIdx.y;

    int seg = 0;
    while (seg + 1 < B && qbase >= rs1[seg + 1]) ++seg;
    const int pstart = rs2[seg];
    const int plen   = rs2[seg + 1] - pstart;
    const int cb = pstart + (int)(((long)plen * part) / NPART);
    const int ce = pstart + (int)(((long)plen * (part + 1)) / NPART);
    const int cnt = ce - cb;

    for (int i = tid; i < cnt; i += 256) {
        const float px = P2[(long)(cb + i) * 3 + 0];
        const float py = P2[(long)(cb + i) * 3 + 1];
        const float pz = P2[(long)(cb + i) * 3 + 2];
        const float pp = __fadd_rn(__fadd_rn(__fmul_rn(px, px), __fmul_rn(py, py)),
                                   __fmul_rn(pz, pz));
        // pre-doubled coords (exact) + pp from original coords
        Pt[i] = make_float4(__fadd_rn(px, px), __fadd_rn(py, py),
                            __fadd_rn(pz, pz), pp);
    }
    __syncthreads();

    float qx[QPT], qy[QPT], qz[QPT], qq[QPT];
    float b0[QPT], b1[QPT], b2[QPT];
    int   i0[QPT], i1[QPT], i2[QPT];
#pragma unroll
    for (int u = 0; u < QPT; ++u) {
        const int q = qbase + u * 256 + tid;
        qx[u] = P1[q * 3 + 0];
        qy[u] = P1[q * 3 + 1];
        qz[u] = P1[q * 3 + 2];
        qq[u] = __fadd_rn(__fadd_rn(__fmul_rn(qx[u], qx[u]), __fmul_rn(qy[u], qy[u])),
                          __fmul_rn(qz[u], qz[u]));
        b0[u] = 3.4e38f; b1[u] = 3.4e38f; b2[u] = 3.4e38f;
        i0[u] = cb; i1[u] = cb; i2[u] = cb;
    }

#pragma unroll 4
    for (int j = 0; j < cnt; ++j) {
        const float4 p = Pt[j];            // wave-uniform broadcast
        const int gj = cb + j;
#pragma unroll
        for (int u = 0; u < QPT; ++u) {
            const float dot2 = fmaf(qz[u], p.z, fmaf(qy[u], p.y, __fmul_rn(qx[u], p.x)));
            const float d2   = __fsub_rn(__fadd_rn(qq[u], p.w), dot2);
            const bool lt0 = d2 < b0[u];
            const bool lt1 = d2 < b1[u];
            const bool lt2 = d2 < b2[u];
            i2[u] = lt1 ? i1[u] : (lt2 ? gj : i2[u]);
            i1[u] = lt0 ? i0[u] : (lt1 ? gj : i1[u]);
            i0[u] = lt0 ? gj : i0[u];
            b2[u] = __builtin_amdgcn_fmed3f(d2, b1[u], b2[u]);
            b1[u] = __builtin_amdgcn_fmed3f(d2, b0[u], b1[u]);
            b0[u] = fminf(b0[u], d2);
        }
    }

#pragma unroll
    for (int u = 0; u < QPT; ++u) {
        const int q = qbase + u * 256 + tid;
        pd[(long)part * N1 + q] = make_float4(b0[u], b1[u], b2[u], 0.f);
        pi[(long)part * N1 + q] = make_int4(i0[u], i1[u], i2[u], 0);
    }
}

// ---------------------------------------------------------------------------
// KNN phase 2: merge NPART partials (ascending partition order => stable).
// ---------------------------------------------------------------------------
__global__ __launch_bounds__(256) void knn3_merge_k(
    const float4* __restrict__ pd, const int4* __restrict__ pi,
    float4* __restrict__ wts, int4* __restrict__ idxout, int N1)
{
    const int q = blockIdx.x * 256 + threadIdx.x;
    if (q >= N1) return;

    float b0 = 3.4e38f, b1 = 3.4e38f, b2 = 3.4e38f;
    int   i0 = 0, i1 = 0, i2 = 0;

    for (int p = 0; p < NPART; ++p) {
        const float4 d = pd[(long)p * N1 + q];
        const int4  ii = pi[(long)p * N1 + q];
        const float dv[3] = {d.x, d.y, d.z};
        const int   iv[3] = {ii.x, ii.y, ii.z};
#pragma unroll
        for (int t = 0; t < 3; ++t) {
            const float dt = dv[t];
            const int   it = iv[t];
            const bool lt0 = dt < b0;
            const bool lt1 = dt < b1;
            const bool lt2 = dt < b2;
            i2 = lt1 ? i1 : (lt2 ? it : i2);
            i1 = lt0 ? i0 : (lt1 ? it : i1);
            i0 = lt0 ? it : i0;
            b2 = __builtin_amdgcn_fmed3f(dt, b1, b2);
            b1 = __builtin_amdgcn_fmed3f(dt, b0, b1);
            b0 = fminf(b0, dt);
        }
    }

    const float d0 = fmaxf(b0, 0.f);
    const float d1 = fmaxf(b1, 0.f);
    const float d2v = fmaxf(b2, 0.f);
    const float w0 = __fdiv_rn(1.0f, __fadd_rn(d0, 1e-8f));
    const float w1 = __fdiv_rn(1.0f, __fadd_rn(d1, 1e-8f));
    const float w2 = __fdiv_rn(1.0f, __fadd_rn(d2v, 1e-8f));
    const float wsum = __fadd_rn(__fadd_rn(w0, w1), w2);
    wts[q]    = make_float4(__fdiv_rn(w0, wsum), __fdiv_rn(w1, wsum),
                            __fdiv_rn(w2, wsum), 0.f);
    idxout[q] = make_int4(i0, i1, i2, 0);
}

// ---------------------------------------------------------------------------
extern "C" void kernel_launch(void* const* d_in, const int* in_sizes, int n_in,
                              void* d_out, int out_size, void* d_ws, size_t ws_size,
                              hipStream_t stream) {
    const float* P1   = (const float*)d_in[0];
    const float* F1   = (const float*)d_in[1];
    const int*   rs1  = (const int*)  d_in[2];
    const float* P2   = (const float*)d_in[3];
    const float* F2in = (const float*)d_in[4];
    const int*   rs2  = (const int*)  d_in[5];
    const float* w1   = (const float*)d_in[6];
    const float* b1   = (const float*)d_in[7];
    const float* g1   = (const float*)d_in[8];
    const float* be1  = (const float*)d_in[9];
    const float* m1   = (const float*)d_in[10];
    const float* v1   = (const float*)d_in[11];
    const float* w2   = (const float*)d_in[12];
    const float* b2   = (const float*)d_in[13];
    const float* g2   = (const float*)d_in[14];
    const float* be2  = (const float*)d_in[15];
    const float* m2   = (const float*)d_in[16];
    const float* v2   = (const float*)d_in[17];

    const int N1  = in_sizes[0] / 3;      // 65536
    const int N2  = in_sizes[3] / 3;      // 16384
    const int CIN = in_sizes[4] / N2;     // 512
    const int B   = in_sizes[2] - 1;      // 4

    // Layout note: f2 ALIASES the pd region — pd/pi are fully consumed by
    // knn3_merge_k before gemm_mfma_k (f2 producer) runs. Keeps ws ~36 MB
    // despite NPART=16.
    char* ws = (char*)d_ws;
    float4* wts = (float4*)ws;  ws += (size_t)N1 * 16;          //  1 MB
    int4*   idx = (int4*)ws;    ws += (size_t)N1 * 16;          //  1 MB
    float4* pd  = (float4*)ws;                                   // 16.8 MB
    float*  f2  = (float*)ws;   ws += (size_t)NPART * N1 * 16;   // (alias)
    int4*   pi  = (int4*)ws;    ws += (size_t)NPART * N1 * 16;   // 16.8 MB
    unsigned short* wb1 = (unsigned short*)ws; ws += (size_t)COUT * COUT * 2;
    unsigned short* wb2 = (unsigned short*)ws;

    cvt_w_k<<<(COUT * COUT + 255) / 256, 256, 0, stream>>>(w1, wb1, COUT * COUT);
    cvt_w_k<<<(COUT * CIN + 255) / 256, 256, 0, stream>>>(w2, wb2, COUT * CIN);

    knn3_part_k<<<dim3(N1 / QPB, NPART), 256, 0, stream>>>(
        P1, P2, rs1, rs2, B, pd, pi, N1);

    knn3_merge_k<<<(N1 + 255) / 256, 256, 0, stream>>>(pd, pi, wts, idx, N1);

    // f2 = relu(bn(feat_2 @ w2^T + b2))   (writes over pd region — safe)
    gemm_mfma_k<<<dim3(N2 / BM, COUT / BNT), 256, 0, stream>>>(
        F2in, wb2, b2, g2, be2, m2, v2, f2, N2, CIN,
        nullptr, nullptr, nullptr);

    // out = relu(bn(feat_1 @ w1^T + b1)) + interp
    gemm_mfma_k<<<dim3(N1 / BM, COUT / BNT), 256, 0, stream>>>(
        F1, wb1, b1, g1, be1, m1, v1, (float*)d_out, N1, COUT,
        f2, wts, idx);
}